// Round 1
// baseline (79755.194 us; speedup 1.0000x reference)
//
#include <hip/hip_runtime.h>
#include <hip/hip_cooperative_groups.h>
#include <math.h>

namespace cg = cooperative_groups;

#define NBLK 256
#define NTHR 512
#define HID  1024
#define NB   64            // batch
#define SEQL 256
#define VOC  2048
#define G4   4096          // 4*HID
#define HB   (HID * NB)    // 65536 floats per [HID][NB] state

__device__ __forceinline__ float sigm(float x) { return 1.0f / (1.0f + expf(-x)); }

// One LSTM layer gate-GEMM + pointwise update for this block's 4 h-columns.
// States are stored transposed: state[col*NB + m].
// KHALF: per-thread K extent (K/2). GATHER: layer-1 one-hot row add.
template<int KHALF, bool GATHER>
__device__ __forceinline__ void cell_phase(
    const float* __restrict__ W, const float* __restrict__ bias, int wrow0,
    const float* __restrict__ seg0T, const float* __restrict__ seg1T,
    const float* __restrict__ grow,
    float* __restrict__ cT, float* __restrict__ hT,
    int m, int col, int kh, int tid, float (*red)[5])
{
    const int k0 = kh * KHALF;
    const float* src;
    int s0;
    if constexpr (GATHER) { src = seg0T; s0 = k0; }          // single 1024 segment
    else                  { src = kh ? seg1T : seg0T; s0 = 0; } // two 1024 segments

    float a0 = 0.f, a1 = 0.f, a2 = 0.f, a3 = 0.f;
    const float* wp = W + (size_t)(wrow0 + k0) * G4 + col;   // wave-uniform
    const float* sp = src + (size_t)s0 * NB + m;             // coalesced per-lane

    #pragma unroll 8
    for (int k = 0; k < KHALF; ++k) {
        const float hv = *sp; sp += NB;
        a0 += wp[0]    * hv;
        a1 += wp[1024] * hv;
        a2 += wp[2048] * hv;
        a3 += wp[3072] * hv;
        wp += G4;
    }

    __syncthreads();
    red[tid][0] = a0; red[tid][1] = a1; red[tid][2] = a2; red[tid][3] = a3;
    __syncthreads();
    if (kh == 0) {
        float f  = a0 + red[tid + 256][0] + bias[col];
        float i  = a1 + red[tid + 256][1] + bias[col + 1024];
        float o  = a2 + red[tid + 256][2] + bias[col + 2048];
        float ct = a3 + red[tid + 256][3] + bias[col + 3072];
        if constexpr (GATHER) {
            f += grow[0]; i += grow[1024]; o += grow[2048]; ct += grow[3072];
        }
        const int idx = col * NB + m;
        const float cn = sigm(f) * cT[idx] + sigm(i) * tanhf(ct);
        cT[idx] = cn;
        hT[idx] = sigm(o) * tanhf(cn);
    }
}

// y(trow) = h3 @ Wout + bout for this block's 2x4 vocab columns.
__device__ __forceinline__ void y_phase(
    const float* __restrict__ Wo, const float* __restrict__ bo,
    const float* __restrict__ h3T, float* __restrict__ out,
    int trow, int v, int m, int kh, int tid, float (*red)[5])
{
    float a0 = 0.f, a1 = 0.f;
    const float* wp = Wo + (size_t)(kh * 512) * VOC + v;     // wave-uniform
    const float* sp = h3T + (size_t)(kh * 512) * NB + m;     // coalesced

    #pragma unroll 8
    for (int k = 0; k < 512; ++k) {
        const float hv = *sp; sp += NB;
        a0 += wp[0] * hv;
        a1 += wp[1] * hv;
        wp += VOC;
    }

    __syncthreads();
    red[tid][0] = a0; red[tid][1] = a1;
    __syncthreads();
    if (kh == 0) {
        a0 += red[tid + 256][0];
        a1 += red[tid + 256][1];
        float* orow = out + ((size_t)trow * NB + m) * VOC;
        orow[v]     = a0 + bo[v];
        orow[v + 1] = a1 + bo[v + 1];
    }
}

__global__ __launch_bounds__(NTHR) void lstm3_fp32(
    const int*   __restrict__ X,
    const float* __restrict__ W1, const float* __restrict__ b1,
    const float* __restrict__ W2, const float* __restrict__ b2,
    const float* __restrict__ W3, const float* __restrict__ b3,
    const float* __restrict__ Wo, const float* __restrict__ bo,
    float* __restrict__ out, float* __restrict__ ws)
{
    cg::grid_group grid = cg::this_grid();
    __shared__ float red[NTHR][5];   // padded stride 5 to spread banks

    // ws layout (floats): hbuf[3 layers][2 slots][HID][NB], cbuf[3][HID][NB]
    float* hbuf = ws;
    float* cbuf = ws + 6 * HB;

    const int tid = threadIdx.x;
    const int m   = tid & 63;
    const int j   = __builtin_amdgcn_readfirstlane((tid >> 6) & 3);
    const int kh  = __builtin_amdgcn_readfirstlane(tid >> 8);
    // XCD-aware column ownership: blocks on one XCD (blk%8) cover a contiguous
    // 128-col region so each 64B weight line is consumed within one XCD's L2.
    const int xcd = blockIdx.x & 7;
    const int grp = blockIdx.x >> 3;            // 0..31
    const int col = xcd * 128 + grp * 4 + j;    // 0..1023 (h column)
    const int vy  = xcd * 256 + grp * 8 + j * 2; // 0..2046 (vocab column pair)

    // zero h (both slots) and c — ws is poisoned each call
    for (int idx = blockIdx.x * NTHR + tid; idx < 9 * HB; idx += NBLK * NTHR)
        ws[idx] = 0.0f;
    grid.sync();

    for (int t = 0; t < SEQL; ++t) {
        const int sp_ = t & 1;       // slot holding h(t-1)
        const int sn_ = sp_ ^ 1;     // slot receiving h(t)

        // ---- phase A: y(t-1) (overlapped) + layer1(t) ----
        if (t > 0)
            y_phase(Wo, bo, hbuf + (4 + sp_) * HB, out, t - 1, vy, m, kh, tid, red);
        {
            const int tok = X[m * SEQL + t];
            const float* grow = W1 + (size_t)tok * G4 + col;   // one-hot row
            cell_phase<512, true>(W1, b1, VOC,
                                  hbuf + sp_ * HB, nullptr, grow,
                                  cbuf, hbuf + sn_ * HB, m, col, kh, tid, red);
        }
        grid.sync();

        // ---- phase B: layer2(t): seg0 = h1(t), seg1 = h2(t-1) ----
        cell_phase<1024, false>(W2, b2, 0,
                                hbuf + sn_ * HB, hbuf + (2 + sp_) * HB, nullptr,
                                cbuf + HB, hbuf + (2 + sn_) * HB, m, col, kh, tid, red);
        grid.sync();

        // ---- phase C: layer3(t): seg0 = h2(t), seg1 = h3(t-1) ----
        cell_phase<1024, false>(W3, b3, 0,
                                hbuf + (2 + sn_) * HB, hbuf + (4 + sp_) * HB, nullptr,
                                cbuf + 2 * HB, hbuf + (4 + sn_) * HB, m, col, kh, tid, red);
        grid.sync();
    }

    // final y(255): h3(255) lives in slot (SEQL)&1 == 0
    y_phase(Wo, bo, hbuf + 4 * HB, out, SEQL - 1, vy, m, kh, tid, red);

    // final states: (h1,c1,h2,c2,h3,c3), each [NB][HID] row-major
    if (kh == 0) {
        const size_t base = (size_t)SEQL * NB * VOC;
        for (int l = 0; l < 3; ++l) {
            out[base + (size_t)(2 * l)     * HB + m * HID + col] =
                hbuf[(2 * l) * HB + col * NB + m];
            out[base + (size_t)(2 * l + 1) * HB + m * HID + col] =
                cbuf[l * HB + col * NB + m];
        }
    }
}

extern "C" void kernel_launch(void* const* d_in, const int* in_sizes, int n_in,
                              void* d_out, int out_size, void* d_ws, size_t ws_size,
                              hipStream_t stream)
{
    const int*   X  = (const int*)  d_in[0];
    const float* W1 = (const float*)d_in[1];
    const float* b1 = (const float*)d_in[2];
    const float* W2 = (const float*)d_in[3];
    const float* b2 = (const float*)d_in[4];
    const float* W3 = (const float*)d_in[5];
    const float* b3 = (const float*)d_in[6];
    const float* Wo = (const float*)d_in[7];
    const float* bo = (const float*)d_in[8];
    float* out = (float*)d_out;
    float* ws  = (float*)d_ws;

    void* args[] = { &X, &W1, &b1, &W2, &b2, &W3, &b3, &Wo, &bo, &out, &ws };
    hipLaunchCooperativeKernel((const void*)lstm3_fp32,
                               dim3(NBLK), dim3(NTHR), args, 0, stream);
}

// Round 2
// 25351.561 us; speedup vs baseline: 3.1460x; 3.1460x over previous
//
#include <hip/hip_runtime.h>
#include <hip/hip_cooperative_groups.h>
#include <math.h>

namespace cg = cooperative_groups;

#define NBLK 256
#define NTHR 512
#define HID  1024
#define NB   64
#define SEQL 256
#define VOC  2048
#define G4   4096

typedef __attribute__((ext_vector_type(8))) short bf16x8;
typedef __attribute__((ext_vector_type(4))) float f32x4;

#define STG_STRIDE 520   // shorts per staged column (512 k + 8 pad) = 1040B, 16B-aligned

struct SmemT {
    short stg_hi[16 * STG_STRIDE];   // 16640 B  staged W chunk, hi bf16, [col][k]
    short stg_lo[16 * STG_STRIDE];   // 16640 B  lo bf16
    f32x4 red[8][64];                //  8192 B  cross-wave K reduction
    float tile[64 * 17];             //  4352 B  reduced C tile (pad 17 vs bank conflict)
    float cst[3 * 4 * 64];           //  3072 B  persistent c state [layer][dh][m]
    int   tok[64];                   //   256 B  tokens for current t
};                                   // total 49152 B

__device__ __forceinline__ float sigm(float x) { return 1.0f / (1.0f + expf(-x)); }

// C[M,16] += A[M,K] * W[K,16cols] using 16x16x32 bf16 MFMA, fp32 weights split
// on the fly into bf16 hi/lo (3 MFMAs).  Result left in sm->tile[row*17+col].
// Gate tiles: local col = gate*4+dh -> global col gate*1024 + cb + dh.
// y tiles:    local col c          -> global col cb + c.
template<int KTOT, int MTILES>
__device__ void run_gemm(SmemT* sm, const float* __restrict__ W, int ldw, int wrow0,
                         const short* __restrict__ Ahi0, const short* __restrict__ Alo0,
                         const short* __restrict__ Ahi1, const short* __restrict__ Alo1,
                         bool gatecols, int cb, int mbase)
{
    constexpr int WPM = 8 / MTILES;      // waves per M-tile (K-split factor)
    constexpr int RPW = 512 / WPM;       // k-rows per wave per chunk
    constexpr int KS  = RPW / 32;        // MFMA k-steps per wave per chunk
    constexpr int NCH = KTOT / 512;      // chunks of 512 k-rows

    const int tid = threadIdx.x;
    const int l   = tid & 63, w = tid >> 6;
    const int c16 = l & 15,  g = l >> 4;
    const int mt  = w / WPM, sub = w % WPM;
    const int sg  = tid & 3, kp  = tid >> 2;                 // staging role
    const int gc  = gatecols ? (sg * HID + cb) : (cb + sg * 4);

    f32x4 acc = {0.f, 0.f, 0.f, 0.f};

    for (int ch = 0; ch < NCH; ++ch) {
        // ---- stage 512 rows x 16 cols: fp32 -> bf16 hi/lo, transposed [col][k] ----
        #pragma unroll
        for (int rep = 0; rep < 2; ++rep) {
            const int kpair = kp + rep * 128;                // 0..255 (pairs of rows)
            const int row   = wrow0 + ch * 512 + kpair * 2;
            const float4 w0 = *(const float4*)(W + (size_t)row * ldw + gc);
            const float4 w1 = *(const float4*)(W + (size_t)(row + 1) * ldw + gc);
            const float* a = (const float*)&w0;
            const float* b = (const float*)&w1;
            #pragma unroll
            for (int c = 0; c < 4; ++c) {
                const uint32_t ua = __float_as_uint(a[c]);
                const uint32_t ub = __float_as_uint(b[c]);
                const uint32_t hi = (ub & 0xFFFF0000u) | (ua >> 16);   // low=even k
                const float la = a[c] - __uint_as_float(ua & 0xFFFF0000u);
                const float lb = b[c] - __uint_as_float(ub & 0xFFFF0000u);
                const uint32_t lo = (__float_as_uint(lb) & 0xFFFF0000u)
                                  | (__float_as_uint(la) >> 16);
                const int off = (sg * 4 + c) * STG_STRIDE + kpair * 2;
                *(uint32_t*)&sm->stg_hi[off] = hi;
                *(uint32_t*)&sm->stg_lo[off] = lo;
            }
        }
        __syncthreads();

        // ---- compute: wave (mt, sub) does RPW k-rows of this chunk ----
        const int kglob0 = ch * 512;
        const short* ahi = (KTOT == 2048 && kglob0 >= 1024) ? Ahi1 : Ahi0;
        const short* alo = (KTOT == 2048 && kglob0 >= 1024) ? Alo1 : Alo0;
        const int kk0 = kglob0 & 1023;
        const size_t arow = (size_t)(mbase + mt * 16 + c16) * HID;
        const short* ah = ahi + arow + kk0 + sub * RPW + g * 8;
        const short* al = alo + arow + kk0 + sub * RPW + g * 8;
        const short* bh = sm->stg_hi + c16 * STG_STRIDE + sub * RPW + g * 8;
        const short* bl = sm->stg_lo + c16 * STG_STRIDE + sub * RPW + g * 8;
        #pragma unroll
        for (int ks = 0; ks < KS; ++ks) {
            const bf16x8 a_hi = *(const bf16x8*)(ah + ks * 32);
            const bf16x8 a_lo = *(const bf16x8*)(al + ks * 32);
            const bf16x8 b_hi = *(const bf16x8*)(bh + ks * 32);
            const bf16x8 b_lo = *(const bf16x8*)(bl + ks * 32);
            acc = __builtin_amdgcn_mfma_f32_16x16x32_bf16(a_hi, b_hi, acc, 0, 0, 0);
            acc = __builtin_amdgcn_mfma_f32_16x16x32_bf16(a_lo, b_hi, acc, 0, 0, 0);
            acc = __builtin_amdgcn_mfma_f32_16x16x32_bf16(a_hi, b_lo, acc, 0, 0, 0);
        }
        __syncthreads();
    }

    // ---- cross-wave K reduce, write C tile to LDS ----
    sm->red[w][l] = acc;
    __syncthreads();
    if (sub == 0) {
        #pragma unroll
        for (int j = 1; j < WPM; ++j) {
            const f32x4 o = sm->red[w + j][l];
            acc[0] += o[0]; acc[1] += o[1]; acc[2] += o[2]; acc[3] += o[3];
        }
        const int r0 = mt * 16 + (l >> 4) * 4;     // verified C/D layout (m89)
        sm->tile[(r0 + 0) * 17 + c16] = acc[0];
        sm->tile[(r0 + 1) * 17 + c16] = acc[1];
        sm->tile[(r0 + 2) * 17 + c16] = acc[2];
        sm->tile[(r0 + 3) * 17 + c16] = acc[3];
    }
    __syncthreads();
}

__device__ void gate_epilogue(SmemT* sm, int layer, const float* __restrict__ bias,
                              const float* __restrict__ W1gather, int hjb,
                              short* __restrict__ Hhi, short* __restrict__ Hlo)
{
    const int tid = threadIdx.x;
    if (tid < 256) {
        const int m = tid & 63, dh = tid >> 6;
        float f  = sm->tile[m * 17 + dh]       + bias[hjb + dh];
        float i  = sm->tile[m * 17 + 4 + dh]   + bias[HID + hjb + dh];
        float o  = sm->tile[m * 17 + 8 + dh]   + bias[2 * HID + hjb + dh];
        float ct = sm->tile[m * 17 + 12 + dh]  + bias[3 * HID + hjb + dh];
        if (W1gather) {   // layer-1 one-hot row add (exact fp32)
            const float* wr = W1gather + (size_t)sm->tok[m] * G4 + hjb + dh;
            f += wr[0]; i += wr[HID]; o += wr[2 * HID]; ct += wr[3 * HID];
        }
        const int ci = (layer * 4 + dh) * 64 + m;
        const float cn = sigm(f) * sm->cst[ci] + sigm(i) * tanhf(ct);
        sm->cst[ci] = cn;
        const float h = sigm(o) * tanhf(cn);
        const uint32_t uh = __float_as_uint(h);
        const float hiF = __uint_as_float(uh & 0xFFFF0000u);
        const float loV = h - hiF;
        const size_t idx = (size_t)m * HID + hjb + dh;
        Hhi[idx] = (short)(uh >> 16);
        Hlo[idx] = (short)(__float_as_uint(loV) >> 16);
    }
}

__device__ void y_epilogue(SmemT* sm, int t, const float* __restrict__ bo,
                           int vc0, int mh, float* __restrict__ out)
{
    const int tid = threadIdx.x;
    const int mloc = tid >> 4, c = tid & 15;      // 32 x 16 = 512 threads
    const float v = sm->tile[mloc * 17 + c] + bo[vc0 + c];
    const int m = mh * 32 + mloc;
    __builtin_nontemporal_store(v, out + ((size_t)t * NB + m) * VOC + vc0 + c);
}

__global__ __launch_bounds__(NTHR, 1) void lstm3_mfma(
    const int*   __restrict__ X,
    const float* __restrict__ W1, const float* __restrict__ b1,
    const float* __restrict__ W2, const float* __restrict__ b2,
    const float* __restrict__ W3, const float* __restrict__ b3,
    const float* __restrict__ Wo, const float* __restrict__ bo,
    float* __restrict__ out, short* __restrict__ hws)
{
    cg::grid_group grid = cg::this_grid();
    __shared__ SmemT sm;

    const int tid = threadIdx.x;
    const int blk = blockIdx.x;
    // XCD-aware tile ownership: same-XCD blocks own adjacent hidden tiles so
    // each 64B weight line is consumed within one XCD's L2.
    const int tile = (blk & 7) * 32 + (blk >> 3);   // 0..255
    const int hjb  = tile * 4;                       // 4 hidden units per block
    const int q    = blk >> 3;
    const int ytile = (blk & 7) * 16 + (q & 15);     // 0..127
    const int mh    = q >> 4;                        // batch half for y
    const int vc0   = ytile * 16;

    // zero h hi/lo state buffers (ws is poisoned each call)
    uint32_t* wz = (uint32_t*)hws;
    for (int i = blk * NTHR + tid; i < 6 * 65536; i += NBLK * NTHR) wz[i] = 0u;
    for (int i = tid; i < 768; i += NTHR) sm.cst[i] = 0.f;
    grid.sync();

    // h state: per (layer, slot): hi[64][1024] + lo[64][1024] bf16 (as short)
    #define HHI(l_, s_) (hws + ((l_) * 2 + (s_)) * 131072)
    #define HLO(l_, s_) (hws + ((l_) * 2 + (s_)) * 131072 + 65536)

    // Diagonal pipeline: superstep s runs L1(t=s), L2(s-1), L3(s-2), y(s-3).
    for (int s = 0; s <= SEQL + 2; ++s) {
        if (s < SEQL && tid < 64) sm.tok[tid] = X[tid * SEQL + s];

        if (s < SEQL) {                       // L1, t = s
            const int t = s, sl = t & 1, sp = sl ^ 1;
            run_gemm<1024, 4>(&sm, W1, G4, VOC, HHI(0, sp), HLO(0, sp),
                              nullptr, nullptr, true, hjb, 0);
            gate_epilogue(&sm, 0, b1, W1, hjb, HHI(0, sl), HLO(0, sl));
        }
        if (s >= 1 && s <= SEQL) {            // L2, t = s-1
            const int t = s - 1, sl = t & 1, sp = sl ^ 1;
            run_gemm<2048, 4>(&sm, W2, G4, 0, HHI(0, sl), HLO(0, sl),
                              HHI(1, sp), HLO(1, sp), true, hjb, 0);
            gate_epilogue(&sm, 1, b2, nullptr, hjb, HHI(1, sl), HLO(1, sl));
        }
        if (s >= 2 && s <= SEQL + 1) {        // L3, t = s-2
            const int t = s - 2, sl = t & 1, sp = sl ^ 1;
            run_gemm<2048, 4>(&sm, W3, G4, 0, HHI(1, sl), HLO(1, sl),
                              HHI(2, sp), HLO(2, sp), true, hjb, 0);
            gate_epilogue(&sm, 2, b3, nullptr, hjb, HHI(2, sl), HLO(2, sl));
        }
        if (s >= 3) {                         // y, t = s-3
            const int t = s - 3, sl = t & 1;
            run_gemm<1024, 2>(&sm, Wo, VOC, 0, HHI(2, sl), HLO(2, sl),
                              nullptr, nullptr, false, vc0, mh * 32);
            y_epilogue(&sm, t, bo, vc0, mh, out);
        }
        grid.sync();
    }

    // final states (h1,c1,h2,c2,h3,c3); t=255 lives in slot 1
    if (tid < 256) {
        const int m = tid & 63, dh = tid >> 6;
        const size_t base = (size_t)SEQL * NB * VOC;
        #pragma unroll
        for (int lyr = 0; lyr < 3; ++lyr) {
            const short* hh = HHI(lyr, 1);
            const short* hl = HLO(lyr, 1);
            const size_t idx = (size_t)m * HID + hjb + dh;
            const float h = __uint_as_float(((uint32_t)(uint16_t)hh[idx]) << 16)
                          + __uint_as_float(((uint32_t)(uint16_t)hl[idx]) << 16);
            out[base + (size_t)(2 * lyr) * 65536 + idx] = h;
            out[base + (size_t)(2 * lyr + 1) * 65536 + idx] =
                sm.cst[(lyr * 4 + dh) * 64 + m];
        }
    }
}

extern "C" void kernel_launch(void* const* d_in, const int* in_sizes, int n_in,
                              void* d_out, int out_size, void* d_ws, size_t ws_size,
                              hipStream_t stream)
{
    const int*   X  = (const int*)  d_in[0];
    const float* W1 = (const float*)d_in[1];
    const float* b1 = (const float*)d_in[2];
    const float* W2 = (const float*)d_in[3];
    const float* b2 = (const float*)d_in[4];
    const float* W3 = (const float*)d_in[5];
    const float* b3 = (const float*)d_in[6];
    const float* Wo = (const float*)d_in[7];
    const float* bo = (const float*)d_in[8];
    float* out = (float*)d_out;
    short* hws = (short*)d_ws;

    void* args[] = { &X, &W1, &b1, &W2, &b2, &W3, &b3, &Wo, &bo, &out, &hws };
    hipLaunchCooperativeKernel((const void*)lstm3_mfma,
                               dim3(NBLK), dim3(NTHR), args, 0, stream);
}

// Round 3
// 24067.873 us; speedup vs baseline: 3.3138x; 1.0533x over previous
//
#include <hip/hip_runtime.h>
#include <hip/hip_cooperative_groups.h>
#include <math.h>

namespace cg = cooperative_groups;

#define NBLK 256
#define NTHR 512
#define HID  1024
#define NB   64
#define SEQL 256
#define VOC  2048
#define G4   4096

typedef __attribute__((ext_vector_type(8))) short bf16x8;
typedef __attribute__((ext_vector_type(4))) float f32x4;

__device__ __forceinline__ float sigm(float x) { return 1.0f / (1.0f + expf(-x)); }

// ============================ FAST PATH ============================
// ws layout (bytes):
//  P1: 128 tiles x 2 chunks x 64KB  = 16 MB   (W1 h-part, bf16 hi/lo, swizzled)
//  P2: 128 tiles x 4 chunks x 64KB  = 32 MB   (W2)
//  P3: 128 tiles x 4 chunks x 64KB  = 32 MB   (W3)
//  PY: 128 tiles x 2 chunks x 32KB  =  8 MB   (Wout)
//  H : 6 x (hi[64][1024] + lo[64][1024]) shorts = 1.5 MB  (h states, dbuf slots)
//  C : 3 x [1024][64] float = 768 KB          (c states)
#define OFF_P1 0u
#define OFF_P2 16777216u
#define OFF_P3 50331648u
#define OFF_PY 83886080u
#define OFF_H  92274688u
#define OFF_C  93847552u
#define WS_NEED 94633984ull

struct SmemF {
    short bbuf[2][32768];   // 2 x 64KB chunk images: hi[32][512] + lo[32][512], swizzled
    float tile[64 * 33];    // C tile (pad 33)
    f32x4 red[8][64];       // y-GEMM cross-wave K reduce
    int   tok[64];
};                          // 147,968 B

// prepack one 64KB gate-chunk image. Image byte b: col L = b>>10 (0..31, hi plane)
// k = ((b&1023) ^ ((L&7)<<4)) >> 1.  col maps L -> gate (L>>3)*1024 + ta*8 + (L&7).
__device__ void prepack_gate(uint32_t* __restrict__ img, const float* __restrict__ W,
                             int row0, int ta)
{
    for (int s = threadIdx.x; s < 16384; s += NTHR) {
        const int b4 = s * 4;
        const int plane = b4 >> 15;
        const int bb = b4 & 32767;
        const int L = bb >> 10;
        const int r = (bb & 1023) ^ ((L & 7) << 4);
        const int k = r >> 1;                       // even
        const int col = (L >> 3) * 1024 + ta * 8 + (L & 7);
        const float v0 = W[(size_t)(row0 + k) * G4 + col];
        const float v1 = W[(size_t)(row0 + k + 1) * G4 + col];
        uint32_t u;
        if (plane == 0) {
            u = (__float_as_uint(v0) >> 16) | (__float_as_uint(v1) & 0xFFFF0000u);
        } else {
            const float l0 = v0 - __uint_as_float(__float_as_uint(v0) & 0xFFFF0000u);
            const float l1 = v1 - __uint_as_float(__float_as_uint(v1) & 0xFFFF0000u);
            u = (__float_as_uint(l0) >> 16) | (__float_as_uint(l1) & 0xFFFF0000u);
        }
        img[s] = u;
    }
}

__device__ void prepack_y(uint32_t* __restrict__ img, const float* __restrict__ Wo,
                          int row0, int ty)
{
    for (int s = threadIdx.x; s < 8192; s += NTHR) {
        const int b4 = s * 4;
        const int plane = b4 >> 14;
        const int bb = b4 & 16383;
        const int L = bb >> 10;                     // 0..15
        const int r = (bb & 1023) ^ ((L & 7) << 4);
        const int k = r >> 1;
        const int col = ty * 16 + L;
        const float v0 = Wo[(size_t)(row0 + k) * VOC + col];
        const float v1 = Wo[(size_t)(row0 + k + 1) * VOC + col];
        uint32_t u;
        if (plane == 0) {
            u = (__float_as_uint(v0) >> 16) | (__float_as_uint(v1) & 0xFFFF0000u);
        } else {
            const float l0 = v0 - __uint_as_float(__float_as_uint(v0) & 0xFFFF0000u);
            const float l1 = v1 - __uint_as_float(__float_as_uint(v1) & 0xFFFF0000u);
            u = (__float_as_uint(l0) >> 16) | (__float_as_uint(l1) & 0xFFFF0000u);
        }
        img[s] = u;
    }
}

// N=32 gate GEMM over full K. wave = (mt 0..3, nt 0..1), 16x16 tile, acc f32x4.
// A planes: hi at A + row*1024 + k, lo at +65536 shorts.
template<int NCH, bool TWOSEG>
__device__ __forceinline__ void gemm_gate(SmemF* sm, const char* __restrict__ pack,
    const short* __restrict__ A0, const short* __restrict__ A1)
{
    const int tid = threadIdx.x;
    const int w = tid >> 6, lane = tid & 63;
    const int mt = w >> 1, nt = w & 1;
    const int c16 = lane & 15, g = lane >> 4;
    const int Lcol = nt * 16 + c16;
    const int swz = (Lcol & 7) << 4;

    f32x4 acc = {0.f, 0.f, 0.f, 0.f};
    uint4 st[8];

    // stage chunk 0
    #pragma unroll
    for (int i = 0; i < 8; ++i)
        st[i] = *(const uint4*)(pack + (i * NTHR + tid) * 16);
    #pragma unroll
    for (int i = 0; i < 8; ++i)
        *(uint4*)((char*)sm->bbuf[0] + (i * NTHR + tid) * 16) = st[i];
    __syncthreads();

    #pragma unroll
    for (int ch = 0; ch < NCH; ++ch) {
        if (ch + 1 < NCH) {                      // issue next-chunk loads early
            const char* src = pack + (size_t)(ch + 1) * 65536;
            #pragma unroll
            for (int i = 0; i < 8; ++i)
                st[i] = *(const uint4*)(src + (i * NTHR + tid) * 16);
        }
        const short* Aseg = (TWOSEG && ch >= 2) ? A1 : A0;
        const int kk0 = (TWOSEG ? (ch & 1) : ch) * 512;
        const short* ah = Aseg + (size_t)(mt * 16 + c16) * 1024 + kk0 + g * 8;
        const short* al = ah + 65536;
        const char* bb = (const char*)sm->bbuf[ch & 1];
        #pragma unroll
        for (int ks = 0; ks < 16; ++ks) {
            const int bofs = (Lcol * 1024 + ks * 64 + g * 16) ^ swz;
            const bf16x8 b_h = *(const bf16x8*)(bb + bofs);
            const bf16x8 b_l = *(const bf16x8*)(bb + 32768 + bofs);
            const bf16x8 a_h = *(const bf16x8*)(ah + ks * 32);
            const bf16x8 a_l = *(const bf16x8*)(al + ks * 32);
            acc = __builtin_amdgcn_mfma_f32_16x16x32_bf16(a_h, b_h, acc, 0, 0, 0);
            acc = __builtin_amdgcn_mfma_f32_16x16x32_bf16(a_l, b_h, acc, 0, 0, 0);
            acc = __builtin_amdgcn_mfma_f32_16x16x32_bf16(a_h, b_l, acc, 0, 0, 0);
        }
        if (ch + 1 < NCH) {                      // write staged regs (T14 late-write)
            #pragma unroll
            for (int i = 0; i < 8; ++i)
                *(uint4*)((char*)sm->bbuf[(ch + 1) & 1] + (i * NTHR + tid) * 16) = st[i];
        }
        __syncthreads();
    }
    const int r0 = mt * 16 + g * 4;              // verified C/D layout (m89)
    sm->tile[(r0 + 0) * 33 + Lcol] = acc[0];
    sm->tile[(r0 + 1) * 33 + Lcol] = acc[1];
    sm->tile[(r0 + 2) * 33 + Lcol] = acc[2];
    sm->tile[(r0 + 3) * 33 + Lcol] = acc[3];
    __syncthreads();
}

// y GEMM: N=16, wave = (mt 0..3, kh 0..1) K-split, reduce via red[].
__device__ __forceinline__ void gemm_y(SmemF* sm, const char* __restrict__ pack,
                                       const short* __restrict__ A0)
{
    const int tid = threadIdx.x;
    const int w = tid >> 6, lane = tid & 63;
    const int mt = w >> 1, kh = w & 1;
    const int c16 = lane & 15, g = lane >> 4;
    const int swz = (c16 & 7) << 4;

    f32x4 acc = {0.f, 0.f, 0.f, 0.f};
    uint4 st[4];
    #pragma unroll
    for (int i = 0; i < 4; ++i)
        st[i] = *(const uint4*)(pack + (i * NTHR + tid) * 16);
    #pragma unroll
    for (int i = 0; i < 4; ++i)
        *(uint4*)((char*)sm->bbuf[0] + (i * NTHR + tid) * 16) = st[i];
    __syncthreads();

    #pragma unroll
    for (int ch = 0; ch < 2; ++ch) {
        if (ch == 0) {
            const char* src = pack + 32768;
            #pragma unroll
            for (int i = 0; i < 4; ++i)
                st[i] = *(const uint4*)(src + (i * NTHR + tid) * 16);
        }
        const int kk0 = ch * 512 + kh * 256;
        const short* ah = A0 + (size_t)(mt * 16 + c16) * 1024 + kk0 + g * 8;
        const short* al = ah + 65536;
        const char* bb = (const char*)sm->bbuf[ch & 1];
        #pragma unroll
        for (int ks = 0; ks < 8; ++ks) {
            const int koff = kh * 256 + ks * 32 + g * 8;
            const int bofs = (c16 * 1024 + koff * 2) ^ swz;
            const bf16x8 b_h = *(const bf16x8*)(bb + bofs);
            const bf16x8 b_l = *(const bf16x8*)(bb + 16384 + bofs);
            const bf16x8 a_h = *(const bf16x8*)(ah + ks * 32);
            const bf16x8 a_l = *(const bf16x8*)(al + ks * 32);
            acc = __builtin_amdgcn_mfma_f32_16x16x32_bf16(a_h, b_h, acc, 0, 0, 0);
            acc = __builtin_amdgcn_mfma_f32_16x16x32_bf16(a_l, b_h, acc, 0, 0, 0);
            acc = __builtin_amdgcn_mfma_f32_16x16x32_bf16(a_h, b_l, acc, 0, 0, 0);
        }
        if (ch == 0) {
            #pragma unroll
            for (int i = 0; i < 4; ++i)
                *(uint4*)((char*)sm->bbuf[1] + (i * NTHR + tid) * 16) = st[i];
        }
        __syncthreads();
    }
    sm->red[w][lane] = acc;
    __syncthreads();
}

__device__ __forceinline__ void gate_epi(SmemF* sm, const float* __restrict__ bias,
    const float* __restrict__ Wgather, float* __restrict__ cst,
    short* __restrict__ Hout, int ta)
{
    const int tid = threadIdx.x;
    const int m = tid & 63, u = tid >> 6;
    const int hb = ta * 8 + u;
    const float* tl = sm->tile + m * 33;
    float f  = tl[u]      + bias[hb];
    float i  = tl[8 + u]  + bias[1024 + hb];
    float o  = tl[16 + u] + bias[2048 + hb];
    float ct = tl[24 + u] + bias[3072 + hb];
    if (Wgather) {                                 // L1 one-hot row add (exact fp32)
        const float* wr = Wgather + (size_t)sm->tok[m] * G4 + hb;
        f += wr[0]; i += wr[1024]; o += wr[2048]; ct += wr[3072];
    }
    float* cp = cst + hb * 64 + m;
    const float cn = sigm(f) * (*cp) + sigm(i) * tanhf(ct);
    *cp = cn;
    const float h = sigm(o) * tanhf(cn);
    const uint32_t uh = __float_as_uint(h);
    const float lof = h - __uint_as_float(uh & 0xFFFF0000u);
    Hout[m * 1024 + hb] = (short)(uh >> 16);
    Hout[65536 + m * 1024 + hb] = (short)(__float_as_uint(lof) >> 16);
}

__device__ __forceinline__ void y_epi(SmemF* sm, int t, const float* __restrict__ bo,
                                      int vc0, float* __restrict__ out)
{
    const int tid = threadIdx.x;
    const int c = tid & 15, m0 = tid >> 4;         // m0 0..31
    #pragma unroll
    for (int hh = 0; hh < 2; ++hh) {
        const int m = m0 + hh * 32;
        const int mt = m >> 4, mr = m & 15;
        const int l = ((mr >> 2) << 4) | c;
        const int i = mr & 3;
        const float v = sm->red[mt * 2][l][i] + sm->red[mt * 2 + 1][l][i] + bo[vc0 + c];
        __builtin_nontemporal_store(v, out + ((size_t)t * NB + m) * VOC + vc0 + c);
    }
    __syncthreads();
}

__device__ __forceinline__ float recon(const short* __restrict__ Hp, size_t idx)
{
    return __uint_as_float(((uint32_t)(uint16_t)Hp[idx]) << 16)
         + __uint_as_float(((uint32_t)(uint16_t)Hp[65536 + idx]) << 16);
}

__global__ __launch_bounds__(NTHR, 2) void lstm3_v3(
    const int*   __restrict__ X,
    const float* __restrict__ W1, const float* __restrict__ b1,
    const float* __restrict__ W2, const float* __restrict__ b2,
    const float* __restrict__ W3, const float* __restrict__ b3,
    const float* __restrict__ Wo, const float* __restrict__ bo,
    float* __restrict__ out, char* __restrict__ wsb)
{
    cg::grid_group grid = cg::this_grid();
    __shared__ SmemF sm;

    const int tid = threadIdx.x, blk = blockIdx.x;
    const bool grpA = blk < 128;
    const int bb_ = grpA ? blk : blk - 128;
    // XCD-aware: same-XCD blocks own adjacent column tiles
    const int ta = (bb_ & 7) * 16 + (bb_ >> 3);    // 0..127

    // zero states (H + C regions)
    uint32_t* zr = (uint32_t*)(wsb + OFF_H);
    for (int i = blk * NTHR + tid; i < 589824; i += NBLK * NTHR) zr[i] = 0u;

    // prepack own weight tiles
    if (grpA) {
        for (int ch = 0; ch < 2; ++ch)
            prepack_gate((uint32_t*)(wsb + OFF_P1 + (size_t)ta * 131072 + ch * 65536),
                         W1, VOC + ch * 512, ta);
        for (int ch = 0; ch < 4; ++ch)
            prepack_gate((uint32_t*)(wsb + OFF_P3 + (size_t)ta * 262144 + ch * 65536),
                         W3, ch * 512, ta);
    } else {
        for (int ch = 0; ch < 4; ++ch)
            prepack_gate((uint32_t*)(wsb + OFF_P2 + (size_t)ta * 262144 + ch * 65536),
                         W2, ch * 512, ta);
        for (int ch = 0; ch < 2; ++ch)
            prepack_y((uint32_t*)(wsb + OFF_PY + (size_t)ta * 65536 + ch * 32768),
                      Wo, ch * 512, ta);
    }
    grid.sync();

    short* H = (short*)(wsb + OFF_H);
    float* C = (float*)(wsb + OFF_C);
    #define HP(l_, s_) (H + ((l_) * 2 + (s_)) * 131072)

    // Diagonal pipeline: superstep s runs L1(t=s) & L3(s-2) on group A,
    // L2(s-1) & y(s-3) on group B. One grid sync per superstep.
    for (int s = 0; s <= SEQL + 2; ++s) {
        if (tid < 64 && s < SEQL) sm.tok[tid] = X[tid * SEQL + s];

        if (grpA) {
            if (s < SEQL) {
                const int sl = s & 1;
                gemm_gate<2, false>(&sm, wsb + OFF_P1 + (size_t)ta * 131072,
                                    HP(0, sl ^ 1), nullptr);
                gate_epi(&sm, b1, W1, C + 0 * 65536, HP(0, sl), ta);
            }
            if (s >= 2 && s <= SEQL + 1) {
                const int t = s - 2, sl = t & 1;
                gemm_gate<4, true>(&sm, wsb + OFF_P3 + (size_t)ta * 262144,
                                   HP(1, sl), HP(2, sl ^ 1));
                gate_epi(&sm, b3, nullptr, C + 2 * 65536, HP(2, sl), ta);
            }
        } else {
            if (s >= 1 && s <= SEQL) {
                const int t = s - 1, sl = t & 1;
                gemm_gate<4, true>(&sm, wsb + OFF_P2 + (size_t)ta * 262144,
                                   HP(0, sl), HP(1, sl ^ 1));
                gate_epi(&sm, b2, nullptr, C + 1 * 65536, HP(1, sl), ta);
            }
            if (s >= 3) {
                const int t = s - 3, sl = t & 1;
                gemm_y(&sm, wsb + OFF_PY + (size_t)ta * 65536, HP(2, sl));
                y_epi(&sm, t, bo, ta * 16, out);
            }
        }
        grid.sync();
    }

    // final states (h1,c1,h2,c2,h3,c3), each [64][1024]; t=255 -> slot 1
    {
        const int m = tid & 63, u = tid >> 6;
        const size_t base = (size_t)SEQL * NB * VOC;
        const size_t idx = (size_t)m * 1024 + ta * 8 + u;
        const int cu = (ta * 8 + u) * 64 + m;
        if (grpA) {
            out[base + idx]               = recon(HP(0, 1), idx);
            out[base + 65536 + idx]       = C[0 * 65536 + cu];
            out[base + 4 * 65536 + idx]   = recon(HP(2, 1), idx);
            out[base + 5 * 65536 + idx]   = C[2 * 65536 + cu];
        } else {
            out[base + 2 * 65536 + idx]   = recon(HP(1, 1), idx);
            out[base + 3 * 65536 + idx]   = C[1 * 65536 + cu];
        }
    }
    #undef HP
}

// ============================ FALLBACK (round-2, used if ws too small) ============================
#define STG_STRIDE 520

struct SmemFB {
    short stg_hi[16 * STG_STRIDE];
    short stg_lo[16 * STG_STRIDE];
    f32x4 red[8][64];
    float tile[64 * 17];
    float cst[3 * 4 * 64];
    int   tok[64];
};

template<int KTOT, int MTILES>
__device__ void fb_gemm(SmemFB* sm, const float* __restrict__ W, int ldw, int wrow0,
                        const short* __restrict__ Ahi0, const short* __restrict__ Alo0,
                        const short* __restrict__ Ahi1, const short* __restrict__ Alo1,
                        bool gatecols, int cb, int mbase)
{
    constexpr int WPM = 8 / MTILES;
    constexpr int RPW = 512 / WPM;
    constexpr int KS  = RPW / 32;
    constexpr int NCH = KTOT / 512;

    const int tid = threadIdx.x;
    const int l   = tid & 63, w = tid >> 6;
    const int c16 = l & 15,  g = l >> 4;
    const int mt  = w / WPM, sub = w % WPM;
    const int sg  = tid & 3, kp  = tid >> 2;
    const int gc  = gatecols ? (sg * HID + cb) : (cb + sg * 4);

    f32x4 acc = {0.f, 0.f, 0.f, 0.f};

    for (int ch = 0; ch < NCH; ++ch) {
        #pragma unroll
        for (int rep = 0; rep < 2; ++rep) {
            const int kpair = kp + rep * 128;
            const int row   = wrow0 + ch * 512 + kpair * 2;
            const float4 w0 = *(const float4*)(W + (size_t)row * ldw + gc);
            const float4 w1 = *(const float4*)(W + (size_t)(row + 1) * ldw + gc);
            const float* a = (const float*)&w0;
            const float* b = (const float*)&w1;
            #pragma unroll
            for (int c = 0; c < 4; ++c) {
                const uint32_t ua = __float_as_uint(a[c]);
                const uint32_t ub = __float_as_uint(b[c]);
                const uint32_t hi = (ub & 0xFFFF0000u) | (ua >> 16);
                const float la = a[c] - __uint_as_float(ua & 0xFFFF0000u);
                const float lb = b[c] - __uint_as_float(ub & 0xFFFF0000u);
                const uint32_t lo = (__float_as_uint(lb) & 0xFFFF0000u)
                                  | (__float_as_uint(la) >> 16);
                const int off = (sg * 4 + c) * STG_STRIDE + kpair * 2;
                *(uint32_t*)&sm->stg_hi[off] = hi;
                *(uint32_t*)&sm->stg_lo[off] = lo;
            }
        }
        __syncthreads();

        const int kglob0 = ch * 512;
        const short* ahi = (KTOT == 2048 && kglob0 >= 1024) ? Ahi1 : Ahi0;
        const short* alo = (KTOT == 2048 && kglob0 >= 1024) ? Alo1 : Alo0;
        const int kk0 = kglob0 & 1023;
        const size_t arow = (size_t)(mbase + mt * 16 + c16) * HID;
        const short* ah = ahi + arow + kk0 + sub * RPW + g * 8;
        const short* al = alo + arow + kk0 + sub * RPW + g * 8;
        const short* bh = sm->stg_hi + c16 * STG_STRIDE + sub * RPW + g * 8;
        const short* bl = sm->stg_lo + c16 * STG_STRIDE + sub * RPW + g * 8;
        #pragma unroll
        for (int ks = 0; ks < KS; ++ks) {
            const bf16x8 a_hi = *(const bf16x8*)(ah + ks * 32);
            const bf16x8 a_lo = *(const bf16x8*)(al + ks * 32);
            const bf16x8 b_hi = *(const bf16x8*)(bh + ks * 32);
            const bf16x8 b_lo = *(const bf16x8*)(bl + ks * 32);
            acc = __builtin_amdgcn_mfma_f32_16x16x32_bf16(a_hi, b_hi, acc, 0, 0, 0);
            acc = __builtin_amdgcn_mfma_f32_16x16x32_bf16(a_lo, b_hi, acc, 0, 0, 0);
            acc = __builtin_amdgcn_mfma_f32_16x16x32_bf16(a_hi, b_lo, acc, 0, 0, 0);
        }
        __syncthreads();
    }

    sm->red[w][l] = acc;
    __syncthreads();
    if (sub == 0) {
        #pragma unroll
        for (int j = 1; j < WPM; ++j) {
            const f32x4 o = sm->red[w + j][l];
            acc[0] += o[0]; acc[1] += o[1]; acc[2] += o[2]; acc[3] += o[3];
        }
        const int r0 = mt * 16 + (l >> 4) * 4;
        sm->tile[(r0 + 0) * 17 + c16] = acc[0];
        sm->tile[(r0 + 1) * 17 + c16] = acc[1];
        sm->tile[(r0 + 2) * 17 + c16] = acc[2];
        sm->tile[(r0 + 3) * 17 + c16] = acc[3];
    }
    __syncthreads();
}

__device__ void fb_gate_epi(SmemFB* sm, int layer, const float* __restrict__ bias,
                            const float* __restrict__ W1gather, int hjb,
                            short* __restrict__ Hhi, short* __restrict__ Hlo)
{
    const int tid = threadIdx.x;
    if (tid < 256) {
        const int m = tid & 63, dh = tid >> 6;
        float f  = sm->tile[m * 17 + dh]       + bias[hjb + dh];
        float i  = sm->tile[m * 17 + 4 + dh]   + bias[HID + hjb + dh];
        float o  = sm->tile[m * 17 + 8 + dh]   + bias[2 * HID + hjb + dh];
        float ct = sm->tile[m * 17 + 12 + dh]  + bias[3 * HID + hjb + dh];
        if (W1gather) {
            const float* wr = W1gather + (size_t)sm->tok[m] * G4 + hjb + dh;
            f += wr[0]; i += wr[HID]; o += wr[2 * HID]; ct += wr[3 * HID];
        }
        const int ci = (layer * 4 + dh) * 64 + m;
        const float cn = sigm(f) * sm->cst[ci] + sigm(i) * tanhf(ct);
        sm->cst[ci] = cn;
        const float h = sigm(o) * tanhf(cn);
        const uint32_t uh = __float_as_uint(h);
        const float hiF = __uint_as_float(uh & 0xFFFF0000u);
        const float loV = h - hiF;
        const size_t idx = (size_t)m * HID + hjb + dh;
        Hhi[idx] = (short)(uh >> 16);
        Hlo[idx] = (short)(__float_as_uint(loV) >> 16);
    }
}

__device__ void fb_y_epi(SmemFB* sm, int t, const float* __restrict__ bo,
                         int vc0, int mh, float* __restrict__ out)
{
    const int tid = threadIdx.x;
    const int mloc = tid >> 4, c = tid & 15;
    const float v = sm->tile[mloc * 17 + c] + bo[vc0 + c];
    const int m = mh * 32 + mloc;
    __builtin_nontemporal_store(v, out + ((size_t)t * NB + m) * VOC + vc0 + c);
}

__global__ __launch_bounds__(NTHR, 1) void lstm3_fb(
    const int*   __restrict__ X,
    const float* __restrict__ W1, const float* __restrict__ b1,
    const float* __restrict__ W2, const float* __restrict__ b2,
    const float* __restrict__ W3, const float* __restrict__ b3,
    const float* __restrict__ Wo, const float* __restrict__ bo,
    float* __restrict__ out, short* __restrict__ hws)
{
    cg::grid_group grid = cg::this_grid();
    __shared__ SmemFB sm;

    const int tid = threadIdx.x;
    const int blk = blockIdx.x;
    const int tile = (blk & 7) * 32 + (blk >> 3);
    const int hjb  = tile * 4;
    const int q    = blk >> 3;
    const int ytile = (blk & 7) * 16 + (q & 15);
    const int mh    = q >> 4;
    const int vc0   = ytile * 16;

    uint32_t* wz = (uint32_t*)hws;
    for (int i = blk * NTHR + tid; i < 6 * 65536; i += NBLK * NTHR) wz[i] = 0u;
    for (int i = tid; i < 768; i += NTHR) sm.cst[i] = 0.f;
    grid.sync();

    #define HHI(l_, s_) (hws + ((l_) * 2 + (s_)) * 131072)
    #define HLO(l_, s_) (hws + ((l_) * 2 + (s_)) * 131072 + 65536)

    for (int s = 0; s <= SEQL + 2; ++s) {
        if (s < SEQL && tid < 64) sm.tok[tid] = X[tid * SEQL + s];

        if (s < SEQL) {
            const int t = s, sl = t & 1, sp = sl ^ 1;
            fb_gemm<1024, 4>(&sm, W1, G4, VOC, HHI(0, sp), HLO(0, sp),
                             nullptr, nullptr, true, hjb, 0);
            fb_gate_epi(&sm, 0, b1, W1, hjb, HHI(0, sl), HLO(0, sl));
        }
        if (s >= 1 && s <= SEQL) {
            const int t = s - 1, sl = t & 1, sp = sl ^ 1;
            fb_gemm<2048, 4>(&sm, W2, G4, 0, HHI(0, sl), HLO(0, sl),
                             HHI(1, sp), HLO(1, sp), true, hjb, 0);
            fb_gate_epi(&sm, 1, b2, nullptr, hjb, HHI(1, sl), HLO(1, sl));
        }
        if (s >= 2 && s <= SEQL + 1) {
            const int t = s - 2, sl = t & 1, sp = sl ^ 1;
            fb_gemm<2048, 4>(&sm, W3, G4, 0, HHI(1, sl), HLO(1, sl),
                             HHI(2, sp), HLO(2, sp), true, hjb, 0);
            fb_gate_epi(&sm, 2, b3, nullptr, hjb, HHI(2, sl), HLO(2, sl));
        }
        if (s >= 3) {
            const int t = s - 3, sl = t & 1;
            fb_gemm<1024, 2>(&sm, Wo, VOC, 0, HHI(2, sl), HLO(2, sl),
                             nullptr, nullptr, false, vc0, mh * 32);
            fb_y_epi(&sm, t, bo, vc0, mh, out);
        }
        grid.sync();
    }

    if (tid < 256) {
        const int m = tid & 63, dh = tid >> 6;
        const size_t base = (size_t)SEQL * NB * VOC;
        #pragma unroll
        for (int lyr = 0; lyr < 3; ++lyr) {
            const short* hh = HHI(lyr, 1);
            const short* hl = HLO(lyr, 1);
            const size_t idx = (size_t)m * HID + hjb + dh;
            const float h = __uint_as_float(((uint32_t)(uint16_t)hh[idx]) << 16)
                          + __uint_as_float(((uint32_t)(uint16_t)hl[idx]) << 16);
            out[base + (size_t)(2 * lyr) * 65536 + idx] = h;
            out[base + (size_t)(2 * lyr + 1) * 65536 + idx] =
                sm.cst[(lyr * 4 + dh) * 64 + m];
        }
    }
    #undef HHI
    #undef HLO
}

extern "C" void kernel_launch(void* const* d_in, const int* in_sizes, int n_in,
                              void* d_out, int out_size, void* d_ws, size_t ws_size,
                              hipStream_t stream)
{
    const int*   X  = (const int*)  d_in[0];
    const float* W1 = (const float*)d_in[1];
    const float* b1 = (const float*)d_in[2];
    const float* W2 = (const float*)d_in[3];
    const float* b2 = (const float*)d_in[4];
    const float* W3 = (const float*)d_in[5];
    const float* b3 = (const float*)d_in[6];
    const float* Wo = (const float*)d_in[7];
    const float* bo = (const float*)d_in[8];
    float* out = (float*)d_out;

    if (ws_size >= WS_NEED) {
        char* wsb = (char*)d_ws;
        void* args[] = { &X, &W1, &b1, &W2, &b2, &W3, &b3, &Wo, &bo, &out, &wsb };
        hipLaunchCooperativeKernel((const void*)lstm3_v3,
                                   dim3(NBLK), dim3(NTHR), args, 0, stream);
    } else {
        short* hws = (short*)d_ws;
        void* args[] = { &X, &W1, &b1, &W2, &b2, &W3, &b3, &Wo, &bo, &out, &hws };
        hipLaunchCooperativeKernel((const void*)lstm3_fb,
                                   dim3(NBLK), dim3(NTHR), args, 0, stream);
    }
}